// Round 1
// baseline (276.156 us; speedup 1.0000x reference)
//
#include <hip/hip_runtime.h>

// loss = -sum_i  dot(s_i, im_i) / ((||s_i||+EPS) * (||im_i||+EPS))
// s, im: fp32 [N=65536, D=512].  Memory-bound row reduction.

#define EPSV 1.1e-13f   // 1e-13 + 1e-14, matches reference

__global__ void zero_out_kernel(float* out) {
    out[0] = 0.0f;
}

__global__ __launch_bounds__(256, 4) void cosdiag_kernel(
        const float4* __restrict__ s,
        const float4* __restrict__ im,
        float* __restrict__ out,
        int nrows) {
    const int lane  = threadIdx.x & 63;
    const int wave  = threadIdx.x >> 6;
    const int wpb   = blockDim.x >> 6;                 // waves per block (4)
    const int gwave = blockIdx.x * wpb + wave;         // global wave id
    const int nwav  = gridDim.x * wpb;                 // total waves

    float acc = 0.0f;  // per-(wave,lane) partial of sum(diag); only lane 0's matters

    for (int row = gwave; row < nrows; row += nwav) {
        const float4* __restrict__ srow = s  + (size_t)row * 128;  // D/4 = 128
        const float4* __restrict__ irow = im + (size_t)row * 128;
        // 16 B/lane coalesced loads: wave covers 1024 B per instruction
        float4 s0 = srow[lane];
        float4 s1 = srow[lane + 64];
        float4 i0 = irow[lane];
        float4 i1 = irow[lane + 64];

        float ss = s0.x*s0.x + s0.y*s0.y + s0.z*s0.z + s0.w*s0.w
                 + s1.x*s1.x + s1.y*s1.y + s1.z*s1.z + s1.w*s1.w;
        float ii = i0.x*i0.x + i0.y*i0.y + i0.z*i0.z + i0.w*i0.w
                 + i1.x*i1.x + i1.y*i1.y + i1.z*i1.z + i1.w*i1.w;
        float dt = s0.x*i0.x + s0.y*i0.y + s0.z*i0.z + s0.w*i0.w
                 + s1.x*i1.x + s1.y*i1.y + s1.z*i1.z + s1.w*i1.w;

        // 64-lane butterfly reduction (wave = 64 on CDNA, not 32)
        #pragma unroll
        for (int off = 32; off > 0; off >>= 1) {
            ss += __shfl_xor(ss, off);
            ii += __shfl_xor(ii, off);
            dt += __shfl_xor(dt, off);
        }

        if (lane == 0) {
            acc += dt / ((sqrtf(ss) + EPSV) * (sqrtf(ii) + EPSV));
        }
    }

    // block reduce: 4 wave partials -> 1 atomic per block
    __shared__ float part[8];
    if (lane == 0) part[wave] = acc;
    __syncthreads();
    if (threadIdx.x == 0) {
        float bs = 0.0f;
        for (int w = 0; w < wpb; ++w) bs += part[w];
        atomicAdd(out, -bs);   // device-scope by default on CDNA
    }
}

extern "C" void kernel_launch(void* const* d_in, const int* in_sizes, int n_in,
                              void* d_out, int out_size, void* d_ws, size_t ws_size,
                              hipStream_t stream) {
    const float* s  = (const float*)d_in[0];
    const float* im = (const float*)d_in[1];
    // d_in[2] = temp (unused by the loss)
    float* out = (float*)d_out;

    const int D = 512;
    const int nrows = in_sizes[0] / D;   // 65536

    // d_out is re-poisoned to 0xAA before every timed launch: zero it first.
    zero_out_kernel<<<1, 1, 0, stream>>>(out);

    const int block = 256;
    const int rows_per_block = block / 64;                       // 4
    int grid = (nrows + rows_per_block - 1) / rows_per_block;    // 16384
    if (grid > 2048) grid = 2048;                                // grid-stride the rest

    cosdiag_kernel<<<grid, block, 0, stream>>>(
        (const float4*)s, (const float4*)im, out, nrows);
}